// Round 1
// baseline (818.753 us; speedup 1.0000x reference)
//
#include <hip/hip_runtime.h>

// ---------------- problem constants ----------------
#define B_ 2
#define S_ 2048
#define HID_ 2048
#define H_ 8
#define D_ 256
// THETA = 10000, ln(10000) = 9.210340371976184

typedef unsigned short u16;
typedef __attribute__((ext_vector_type(8))) short bf16x8;   // 8 bf16 in 4 VGPRs
typedef __attribute__((ext_vector_type(4))) float f32x4;

__device__ __forceinline__ u16 f2b(float x) {
    unsigned u = __float_as_uint(x);
    unsigned rb = (u >> 16) & 1u;
    u += 0x7fffu + rb;               // round-to-nearest-even
    return (u16)(u >> 16);
}

// ---------------- fp32 -> bf16 convert ----------------
__global__ __launch_bounds__(256) void cvt_bf16(const float* __restrict__ in,
                                                u16* __restrict__ out, int n) {
    int i = (blockIdx.x * 256 + threadIdx.x) * 4;
    if (i >= n) return;
    float4 f = *(const float4*)(in + i);
    union { u16 u[4]; uint2 v; } pk;
    pk.u[0] = f2b(f.x); pk.u[1] = f2b(f.y); pk.u[2] = f2b(f.z); pk.u[3] = f2b(f.w);
    *(uint2*)(out + i) = pk.v;
}

// ---------------- RoPE: fp32 (B,S,nH,D) -> bf16 (B,S,nH,D) ----------------
__global__ __launch_bounds__(256) void rope_kernel(const float* __restrict__ x,
                                                   const int* __restrict__ pos_ids,
                                                   u16* __restrict__ out, int nHeads) {
    int idx = blockIdx.x * 256 + threadIdx.x;   // over B*S*nHeads*128
    int d   = idx & 127;
    int tmp = idx >> 7;
    int h   = tmp % nHeads;
    int n   = tmp / nHeads;                     // n = b*S + s
    int pos = pos_ids[n];
    float ang = (float)pos * expf(-(float)d * (9.210340371976184f / 128.0f));
    float s, c;
    sincosf(ang, &s, &c);
    size_t base = ((size_t)n * nHeads + h) * D_;
    float x1 = x[base + d], x2 = x[base + d + 128];
    out[base + d]       = f2b(c * x1 - s * x2);
    out[base + d + 128] = f2b(s * x1 + c * x2);
}

// ---------------- V transpose: fp32 (B,S,D) -> bf16 (B,D,S) ----------------
__global__ __launch_bounds__(256) void transpose_v(const float* __restrict__ v,
                                                   u16* __restrict__ vT) {
    __shared__ float t[32][33];
    int b = blockIdx.z;
    int s0 = blockIdx.x * 32, d0 = blockIdx.y * 32;
    int tx = threadIdx.x, ty = threadIdx.y;     // 32 x 8
#pragma unroll
    for (int i = 0; i < 4; ++i)
        t[ty + i * 8][tx] = v[(size_t)b * S_ * D_ + (size_t)(s0 + ty + i * 8) * D_ + d0 + tx];
    __syncthreads();
#pragma unroll
    for (int i = 0; i < 4; ++i)
        vT[(size_t)b * D_ * S_ + (size_t)(d0 + ty + i * 8) * S_ + s0 + tx] = f2b(t[tx][ty + i * 8]);
}

// ---------------- in-place row softmax over attn region ----------------
// rows = B*H*S, each row has S fp32 scores; x = score*1/16 + mask[b,col]
__global__ __launch_bounds__(256) void softmax_rows(float* __restrict__ attn,
                                                    const float* __restrict__ mask) {
    int row = blockIdx.x;                       // (b*H + h)*S + n
    int b = row >> 14;                          // row / (H_*S_)
    float* p = attn + (size_t)row * S_;
    const float* mb = mask + (size_t)b * S_;
    int t = threadIdx.x;
    const float sc = 0.0625f;                   // D^-0.5 = 1/16

    float4 v0 = *(float4*)(p + t * 4);
    float4 v1 = *(float4*)(p + 1024 + t * 4);
    float4 m0 = *(const float4*)(mb + t * 4);
    float4 m1 = *(const float4*)(mb + 1024 + t * 4);
    float x[8] = { v0.x * sc + m0.x, v0.y * sc + m0.y, v0.z * sc + m0.z, v0.w * sc + m0.w,
                   v1.x * sc + m1.x, v1.y * sc + m1.y, v1.z * sc + m1.z, v1.w * sc + m1.w };

    float mx = x[0];
#pragma unroll
    for (int j = 1; j < 8; ++j) mx = fmaxf(mx, x[j]);
#pragma unroll
    for (int o = 32; o > 0; o >>= 1) mx = fmaxf(mx, __shfl_down(mx, o));
    __shared__ float redm[4], reds[4];
    int lane = t & 63, w = t >> 6;
    if (lane == 0) redm[w] = mx;
    __syncthreads();
    mx = fmaxf(fmaxf(redm[0], redm[1]), fmaxf(redm[2], redm[3]));

    float e[8], s = 0.f;
#pragma unroll
    for (int j = 0; j < 8; ++j) { e[j] = expf(x[j] - mx); s += e[j]; }
#pragma unroll
    for (int o = 32; o > 0; o >>= 1) s += __shfl_down(s, o);
    if (lane == 0) reds[w] = s;
    __syncthreads();
    s = reds[0] + reds[1] + reds[2] + reds[3];
    float inv = 1.f / s;

    float4 o0 = { e[0] * inv, e[1] * inv, e[2] * inv, e[3] * inv };
    float4 o1 = { e[4] * inv, e[5] * inv, e[6] * inv, e[7] * inv };
    *(float4*)(p + t * 4) = o0;
    *(float4*)(p + 1024 + t * 4) = o1;
}

// ---------------- batched NT GEMM: C = A(MxK) * B(NxK)^T (+bias) ----------------
// A is bf16 (u16) or fp32 (converted during staging). C is fp32 or bf16.
// blockIdx.z -> (bb = z/numH, hh = z%numH); per-operand batch/head strides in elements.
#define TILE_M 128
#define TILE_N 128
#define TILE_K 32
#define LDSK 40

template <bool A_IS_F32, bool C_IS_BF16>
__global__ __launch_bounds__(256, 2) void gemm_bt(
    const void* __restrict__ Ap, const u16* __restrict__ Bp, void* __restrict__ Cp,
    const float* __restrict__ bias, int M, int N, int K, int lda, int ldb, int ldc,
    long sAb, long sAh, long sBb, long sBh, long sCb, long sCh, int numH) {
    __shared__ __align__(16) u16 As[TILE_M * LDSK];
    __shared__ __align__(16) u16 Bs[TILE_N * LDSK];

    int z = blockIdx.z;
    int bb = z / numH, hh = z % numH;
    const u16* A16 = nullptr;
    const float* Af = nullptr;
    if constexpr (A_IS_F32) Af = (const float*)Ap + (long)bb * sAb + (long)hh * sAh;
    else                    A16 = (const u16*)Ap + (long)bb * sAb + (long)hh * sAh;
    const u16* Bb = Bp + (long)bb * sBb + (long)hh * sBh;
    char* Cb = (char*)Cp;
    long cOff = (long)bb * sCb + (long)hh * sCh;

    const int m0 = blockIdx.y * TILE_M;
    const int n0 = blockIdx.x * TILE_N;
    const int tid = threadIdx.x;
    const int lane = tid & 63, wave = tid >> 6;
    const int l15 = lane & 15, quad = lane >> 4;
    const int waveM = wave >> 1, waveN = wave & 1;

    f32x4 acc[4][4];
#pragma unroll
    for (int mt = 0; mt < 4; ++mt)
#pragma unroll
        for (int nt = 0; nt < 4; ++nt)
#pragma unroll
            for (int r = 0; r < 4; ++r) acc[mt][nt][r] = 0.f;

    for (int k0 = 0; k0 < K; k0 += TILE_K) {
#pragma unroll
        for (int i = 0; i < 2; ++i) {
            int c = tid + i * 256;              // 512 chunks of 8 elements
            int row = c >> 2, col = (c & 3) * 8;
            if constexpr (A_IS_F32) {
                const float* src = Af + (size_t)(m0 + row) * lda + k0 + col;
                float4 f0 = *(const float4*)src;
                float4 f1 = *(const float4*)(src + 4);
                union { u16 u[8]; uint4 v; } pk;
                pk.u[0] = f2b(f0.x); pk.u[1] = f2b(f0.y); pk.u[2] = f2b(f0.z); pk.u[3] = f2b(f0.w);
                pk.u[4] = f2b(f1.x); pk.u[5] = f2b(f1.y); pk.u[6] = f2b(f1.z); pk.u[7] = f2b(f1.w);
                *(uint4*)&As[row * LDSK + col] = pk.v;
            } else {
                *(uint4*)&As[row * LDSK + col] =
                    *(const uint4*)(A16 + (size_t)(m0 + row) * lda + k0 + col);
            }
            *(uint4*)&Bs[row * LDSK + col] =
                *(const uint4*)(Bb + (size_t)(n0 + row) * ldb + k0 + col);
        }
        __syncthreads();

        bf16x8 av[4], bv[4];
#pragma unroll
        for (int t = 0; t < 4; ++t) {
            av[t] = *(bf16x8*)&As[(waveM * 64 + t * 16 + l15) * LDSK + quad * 8];
            bv[t] = *(bf16x8*)&Bs[(waveN * 64 + t * 16 + l15) * LDSK + quad * 8];
        }
#pragma unroll
        for (int mt = 0; mt < 4; ++mt)
#pragma unroll
            for (int nt = 0; nt < 4; ++nt)
                acc[mt][nt] = __builtin_amdgcn_mfma_f32_16x16x32_bf16(av[mt], bv[nt],
                                                                      acc[mt][nt], 0, 0, 0);
        __syncthreads();
    }

    // epilogue: C/D layout col = lane&15, row = quad*4 + r
#pragma unroll
    for (int mt = 0; mt < 4; ++mt) {
        int row = m0 + waveM * 64 + mt * 16 + quad * 4;
#pragma unroll
        for (int nt = 0; nt < 4; ++nt) {
            int col = n0 + waveN * 64 + nt * 16 + l15;
            float bia = bias ? bias[col] : 0.f;
#pragma unroll
            for (int r = 0; r < 4; ++r) {
                float val = acc[mt][nt][r] + bia;
                if constexpr (C_IS_BF16)
                    ((u16*)Cb)[cOff + (size_t)(row + r) * ldc + col] = f2b(val);
                else
                    ((float*)Cb)[cOff + (size_t)(row + r) * ldc + col] = val;
            }
        }
    }
}

// ---------------- host launcher ----------------
extern "C" void kernel_launch(void* const* d_in, const int* in_sizes, int n_in,
                              void* d_out, int out_size, void* d_ws, size_t ws_size,
                              hipStream_t stream) {
    const float* hs   = (const float*)d_in[0];
    const float* mask = (const float*)d_in[1];
    const int*   pos  = (const int*)d_in[2];
    const float* Wq = (const float*)d_in[3];
    const float* bq = (const float*)d_in[4];
    const float* Wk = (const float*)d_in[5];
    const float* bk = (const float*)d_in[6];
    const float* Wv = (const float*)d_in[7];
    const float* bv = (const float*)d_in[8];
    const float* Wo = (const float*)d_in[9];
    const float* bo = (const float*)d_in[10];

    float* out  = (float*)d_out;                         // (B,S,HID)
    float* attn = (float*)d_out + (size_t)B_ * S_ * HID_; // (B,H,S,S)

    // workspace layout (bytes)
    char* ws = (char*)d_ws;
    u16* hs_b   = (u16*)ws;                       ws += (size_t)B_ * S_ * HID_ * 2;   // 16 MB (reused as ctx later)
    u16* Wq_b   = (u16*)ws;                       ws += (size_t)H_ * D_ * HID_ * 2;   // 8 MB
    u16* Wk_b   = (u16*)ws;                       ws += (size_t)D_ * HID_ * 2;        // 1 MB
    u16* Wv_b   = (u16*)ws;                       ws += (size_t)D_ * HID_ * 2;        // 1 MB
    u16* Wo_b   = (u16*)ws;                       ws += (size_t)HID_ * H_ * D_ * 2;   // 8 MB
    float* q_f  = (float*)ws;                     ws += (size_t)B_ * S_ * H_ * D_ * 4; // 32 MB
    float* k_f  = (float*)ws;                     ws += (size_t)B_ * S_ * D_ * 4;     // 4 MB
    float* v_f  = (float*)ws;                     ws += (size_t)B_ * S_ * D_ * 4;     // 4 MB
    u16* q_b    = (u16*)ws;                       ws += (size_t)B_ * S_ * H_ * D_ * 2; // 16 MB
    u16* k_b    = (u16*)ws;                       ws += (size_t)B_ * S_ * D_ * 2;     // 2 MB
    u16* vT_b   = (u16*)ws;                       ws += (size_t)B_ * D_ * S_ * 2;     // 2 MB
    u16* ctx_b  = hs_b;                           // reuse: hs_bf16 dead after QKV projections

    // 1) convert inputs/weights to bf16
    cvt_bf16<<<dim3((B_ * S_ * HID_) / 1024), 256, 0, stream>>>(hs, hs_b, B_ * S_ * HID_);
    cvt_bf16<<<dim3((H_ * D_ * HID_) / 1024), 256, 0, stream>>>(Wq, Wq_b, H_ * D_ * HID_);
    cvt_bf16<<<dim3((D_ * HID_) / 1024), 256, 0, stream>>>(Wk, Wk_b, D_ * HID_);
    cvt_bf16<<<dim3((D_ * HID_) / 1024), 256, 0, stream>>>(Wv, Wv_b, D_ * HID_);
    cvt_bf16<<<dim3((HID_ * H_ * D_) / 1024), 256, 0, stream>>>(Wo, Wo_b, HID_ * H_ * D_);

    // 2) QKV projections (NT GEMMs), fp32 outputs
    gemm_bt<false, false><<<dim3((H_ * D_) / TILE_N, (B_ * S_) / TILE_M, 1), 256, 0, stream>>>(
        hs_b, Wq_b, q_f, bq, B_ * S_, H_ * D_, HID_, HID_, HID_, H_ * D_,
        0, 0, 0, 0, 0, 0, 1);
    gemm_bt<false, false><<<dim3(D_ / TILE_N, (B_ * S_) / TILE_M, 1), 256, 0, stream>>>(
        hs_b, Wk_b, k_f, bk, B_ * S_, D_, HID_, HID_, HID_, D_,
        0, 0, 0, 0, 0, 0, 1);
    gemm_bt<false, false><<<dim3(D_ / TILE_N, (B_ * S_) / TILE_M, 1), 256, 0, stream>>>(
        hs_b, Wv_b, v_f, bv, B_ * S_, D_, HID_, HID_, HID_, D_,
        0, 0, 0, 0, 0, 0, 1);

    // 3) RoPE -> bf16 q,k ; transpose v -> bf16 (B,D,S)
    rope_kernel<<<dim3((B_ * S_ * H_ * 128) / 256), 256, 0, stream>>>(q_f, pos, q_b, H_);
    rope_kernel<<<dim3((B_ * S_ * 1 * 128) / 256), 256, 0, stream>>>(k_f, pos, k_b, 1);
    transpose_v<<<dim3(S_ / 32, D_ / 32, B_), dim3(32, 8), 0, stream>>>(v_f, vT_b);

    // 4) scores = q @ k^T  -> raw fp32 into attn region of d_out
    gemm_bt<false, false><<<dim3(S_ / TILE_N, S_ / TILE_M, B_ * H_), 256, 0, stream>>>(
        q_b, k_b, attn, nullptr, S_, S_, D_, H_ * D_, D_, S_,
        (long)S_ * H_ * D_, D_,                 // A batch/head strides (q)
        (long)S_ * D_, 0,                       // B batch/head strides (k)
        (long)H_ * S_ * S_, (long)S_ * S_,      // C strides (attn)
        H_);

    // 5) softmax in place (scale + mask + normalize) -> attn output
    softmax_rows<<<dim3(B_ * H_ * S_), 256, 0, stream>>>(attn, mask);

    // 6) ctx = attn @ V  (A fp32 converted in staging, B = vT bf16, C bf16)
    gemm_bt<true, true><<<dim3(D_ / TILE_N, S_ / TILE_M, B_ * H_), 256, 0, stream>>>(
        attn, vT_b, ctx_b, nullptr, S_, D_, S_, S_, S_, H_ * D_,
        (long)H_ * S_ * S_, (long)S_ * S_,      // A strides (attn)
        (long)D_ * S_, 0,                       // B strides (vT)
        (long)S_ * H_ * D_, D_,                 // C strides (ctx: col offset h*D)
        H_);

    // 7) out = ctx @ Wo^T + bo  -> fp32 into d_out
    gemm_bt<false, false><<<dim3(HID_ / TILE_N, (B_ * S_) / TILE_M, 1), 256, 0, stream>>>(
        ctx_b, Wo_b, out, bo, B_ * S_, HID_, H_ * D_, H_ * D_, H_ * D_, HID_,
        0, 0, 0, 0, 0, 0, 1);
}

// Round 2
// 751.758 us; speedup vs baseline: 1.0891x; 1.0891x over previous
//
#include <hip/hip_runtime.h>

// ---------------- problem constants ----------------
#define B_ 2
#define S_ 2048
#define HID_ 2048
#define H_ 8
#define D_ 256
#define NQKV 2560   // H*D + D + D
// THETA = 10000, ln(10000) = 9.210340371976184

typedef unsigned short u16;
typedef __attribute__((ext_vector_type(8))) short bf16x8;   // 8 bf16 in 4 VGPRs
typedef __attribute__((ext_vector_type(4))) float f32x4;

__device__ __forceinline__ u16 f2b(float x) {
    unsigned u = __float_as_uint(x);
    unsigned rb = (u >> 16) & 1u;
    u += 0x7fffu + rb;               // round-to-nearest-even
    return (u16)(u >> 16);
}

__device__ __forceinline__ void load_lds16(const u16* g, u16* l) {
    // async 16B/lane global->LDS; HW writes lane i at l + i*16B (wave-uniform base)
    __builtin_amdgcn_global_load_lds(
        (const __attribute__((address_space(1))) void*)g,
        (__attribute__((address_space(3))) void*)l, 16, 0, 0);
}

// ---------------- fp32 -> bf16 convert ----------------
__global__ __launch_bounds__(256) void cvt_bf16(const float* __restrict__ in,
                                                u16* __restrict__ out, int n) {
    int i = (blockIdx.x * 256 + threadIdx.x) * 4;
    if (i >= n) return;
    float4 f = *(const float4*)(in + i);
    union { u16 u[4]; uint2 v; } pk;
    pk.u[0] = f2b(f.x); pk.u[1] = f2b(f.y); pk.u[2] = f2b(f.z); pk.u[3] = f2b(f.w);
    *(uint2*)(out + i) = pk.v;
}

__global__ __launch_bounds__(256) void concat_bias(const float* __restrict__ bq,
                                                   const float* __restrict__ bk,
                                                   const float* __restrict__ bv,
                                                   float* __restrict__ dst) {
    int i = blockIdx.x * 256 + threadIdx.x;
    if (i >= NQKV) return;
    float v;
    if (i < H_ * D_) v = bq[i];
    else if (i < H_ * D_ + D_) v = bk[i - H_ * D_];
    else v = bv[i - H_ * D_ - D_];
    dst[i] = v;
}

// ---------------- RoPE: fp32 strided src -> bf16 (B,S,nH,D) ----------------
__global__ __launch_bounds__(256) void rope_kernel(const float* __restrict__ x,
                                                   int rowStride, int colOff,
                                                   const int* __restrict__ pos_ids,
                                                   u16* __restrict__ out, int nHeads) {
    int idx = blockIdx.x * 256 + threadIdx.x;   // over B*S*nHeads*128
    int d   = idx & 127;
    int tmp = idx >> 7;
    int h   = tmp % nHeads;
    int n   = tmp / nHeads;                     // n = b*S + s
    int pos = pos_ids[n];
    float ang = (float)pos * expf(-(float)d * (9.210340371976184f / 128.0f));
    float s, c;
    sincosf(ang, &s, &c);
    size_t src = (size_t)n * rowStride + colOff + (size_t)h * D_;
    float x1 = x[src + d], x2 = x[src + d + 128];
    size_t dst = ((size_t)n * nHeads + h) * D_;
    out[dst + d]       = f2b(c * x1 - s * x2);
    out[dst + d + 128] = f2b(s * x1 + c * x2);
}

// ---------------- V transpose: fp32 strided (B,S,D) -> bf16 (B,D,S) ----------------
__global__ __launch_bounds__(256) void transpose_v(const float* __restrict__ v,
                                                   int rowStride, int colOff,
                                                   u16* __restrict__ vT) {
    __shared__ float t[32][33];
    int b = blockIdx.z;
    int s0 = blockIdx.x * 32, d0 = blockIdx.y * 32;
    int tx = threadIdx.x, ty = threadIdx.y;     // 32 x 8
#pragma unroll
    for (int i = 0; i < 4; ++i)
        t[ty + i * 8][tx] = v[((size_t)b * S_ + s0 + ty + i * 8) * rowStride + colOff + d0 + tx];
    __syncthreads();
#pragma unroll
    for (int i = 0; i < 4; ++i)
        vT[(size_t)b * D_ * S_ + (size_t)(d0 + ty + i * 8) * S_ + s0 + tx] = f2b(t[tx][ty + i * 8]);
}

// ---------------- in-place row softmax; also emits optional bf16 copy ----------------
__global__ __launch_bounds__(256) void softmax_rows(float* __restrict__ attn,
                                                    const float* __restrict__ mask,
                                                    u16* __restrict__ attn_b) {
    int row = blockIdx.x;                       // (b*H + h)*S + n
    int b = row >> 14;                          // row / (H_*S_)
    float* p = attn + (size_t)row * S_;
    const float* mb = mask + (size_t)b * S_;
    int t = threadIdx.x;
    const float sc = 0.0625f;                   // D^-0.5 = 1/16

    float4 v0 = *(float4*)(p + t * 4);
    float4 v1 = *(float4*)(p + 1024 + t * 4);
    float4 m0 = *(const float4*)(mb + t * 4);
    float4 m1 = *(const float4*)(mb + 1024 + t * 4);
    float x[8] = { v0.x * sc + m0.x, v0.y * sc + m0.y, v0.z * sc + m0.z, v0.w * sc + m0.w,
                   v1.x * sc + m1.x, v1.y * sc + m1.y, v1.z * sc + m1.z, v1.w * sc + m1.w };

    float mx = x[0];
#pragma unroll
    for (int j = 1; j < 8; ++j) mx = fmaxf(mx, x[j]);
#pragma unroll
    for (int o = 32; o > 0; o >>= 1) mx = fmaxf(mx, __shfl_down(mx, o));
    __shared__ float redm[4], reds[4];
    int lane = t & 63, w = t >> 6;
    if (lane == 0) redm[w] = mx;
    __syncthreads();
    mx = fmaxf(fmaxf(redm[0], redm[1]), fmaxf(redm[2], redm[3]));

    float e[8], s = 0.f;
#pragma unroll
    for (int j = 0; j < 8; ++j) { e[j] = expf(x[j] - mx); s += e[j]; }
#pragma unroll
    for (int o = 32; o > 0; o >>= 1) s += __shfl_down(s, o);
    if (lane == 0) reds[w] = s;
    __syncthreads();
    s = reds[0] + reds[1] + reds[2] + reds[3];
    float inv = 1.f / s;

    float o8[8];
#pragma unroll
    for (int j = 0; j < 8; ++j) o8[j] = e[j] * inv;
    *(float4*)(p + t * 4)        = make_float4(o8[0], o8[1], o8[2], o8[3]);
    *(float4*)(p + 1024 + t * 4) = make_float4(o8[4], o8[5], o8[6], o8[7]);

    if (attn_b) {
        u16* pb = attn_b + (size_t)row * S_;
        union { u16 u[4]; uint2 v; } k0, k1;
#pragma unroll
        for (int j = 0; j < 4; ++j) { k0.u[j] = f2b(o8[j]); k1.u[j] = f2b(o8[4 + j]); }
        *(uint2*)(pb + t * 4)        = k0.v;
        *(uint2*)(pb + 1024 + t * 4) = k1.v;
    }
}

// ================= async-staged NT GEMM (m97 structure + XOR swizzle) =================
// C(MxN) = A(MxK) * B(NxK)^T (+bias). A,B bf16. C fp32 or bf16.
#define TILE_M 128
#define TILE_N 128
#define TILE_K 32

template <bool C_IS_BF16>
__global__ __launch_bounds__(256, 2) void gemm_async(
    const u16* __restrict__ Ap, const u16* __restrict__ Bp, void* __restrict__ Cp,
    const float* __restrict__ bias, int lda, int ldb, int ldc, int K,
    long sAb, long sAh, long sBb, long sBh, long sCb, long sCh, int numH) {
    __shared__ __align__(16) u16 As[TILE_M * TILE_K];
    __shared__ __align__(16) u16 Bs[TILE_N * TILE_K];

    int z = blockIdx.z;
    int bb = z / numH, hh = z % numH;
    const u16* Ab = Ap + (long)bb * sAb + (long)hh * sAh;
    const u16* Bb = Bp + (long)bb * sBb + (long)hh * sBh;
    long cOff = (long)bb * sCb + (long)hh * sCh;

    const int m0 = blockIdx.y * TILE_M;
    const int n0 = blockIdx.x * TILE_N;
    const int tid = threadIdx.x;
    const int lane = tid & 63, wave = tid >> 6;
    const int l15 = lane & 15, quad = lane >> 4;
    const int waveM = wave >> 1, waveN = wave & 1;

    f32x4 acc[4][4];
#pragma unroll
    for (int mt = 0; mt < 4; ++mt)
#pragma unroll
        for (int nt = 0; nt < 4; ++nt)
#pragma unroll
            for (int r = 0; r < 4; ++r) acc[mt][nt][r] = 0.f;

    // per-thread staging geometry (fixed over k-loop)
    // chunk c = i*256 + tid; LDS element offset = c*8 (HW: wave base + lane*16B)
    int rowS[2], colS[2];
    u16 *lA[2], *lB[2];
#pragma unroll
    for (int i = 0; i < 2; ++i) {
        int c = i * 256 + tid;
        rowS[i] = c >> 2;
        colS[i] = (((c & 3) ^ ((rowS[i] >> 1) & 3)) * 8);   // XOR-swizzled K-group
        lA[i] = As + (size_t)(i * 256 + wave * 64) * 8;
        lB[i] = Bs + (size_t)(i * 256 + wave * 64) * 8;
    }

    for (int k0 = 0; k0 < K; k0 += TILE_K) {
#pragma unroll
        for (int i = 0; i < 2; ++i) {
            load_lds16(Ab + (size_t)(m0 + rowS[i]) * lda + k0 + colS[i], lA[i]);
            load_lds16(Bb + (size_t)(n0 + rowS[i]) * ldb + k0 + colS[i], lB[i]);
        }
        __syncthreads();   // drains vmcnt (global_load_lds) per barrier semantics

        bf16x8 av[4], bv[4];
#pragma unroll
        for (int t = 0; t < 4; ++t) {
            int ra = waveM * 64 + t * 16 + l15;
            av[t] = *(bf16x8*)&As[ra * TILE_K + ((quad ^ ((ra >> 1) & 3)) * 8)];
            int rb = waveN * 64 + t * 16 + l15;
            bv[t] = *(bf16x8*)&Bs[rb * TILE_K + ((quad ^ ((rb >> 1) & 3)) * 8)];
        }
#pragma unroll
        for (int mt = 0; mt < 4; ++mt)
#pragma unroll
            for (int nt = 0; nt < 4; ++nt)
                acc[mt][nt] = __builtin_amdgcn_mfma_f32_16x16x32_bf16(av[mt], bv[nt],
                                                                      acc[mt][nt], 0, 0, 0);
        __syncthreads();
    }

    // epilogue: C/D layout col = lane&15, row = quad*4 + r
#pragma unroll
    for (int mt = 0; mt < 4; ++mt) {
        int row = m0 + waveM * 64 + mt * 16 + quad * 4;
#pragma unroll
        for (int nt = 0; nt < 4; ++nt) {
            int col = n0 + waveN * 64 + nt * 16 + l15;
            float bia = bias ? bias[col] : 0.f;
#pragma unroll
            for (int r = 0; r < 4; ++r) {
                float val = acc[mt][nt][r] + bia;
                if constexpr (C_IS_BF16)
                    ((u16*)Cp)[cOff + (size_t)(row + r) * ldc + col] = f2b(val);
                else
                    ((float*)Cp)[cOff + (size_t)(row + r) * ldc + col] = val;
            }
        }
    }
}

// ---------------- fallback GEMM (A fp32, staged via VGPR) — used only if ws too small ----
#define LDSK 40
__global__ __launch_bounds__(256, 2) void gemm_slow_f32a(
    const float* __restrict__ Ap, const u16* __restrict__ Bp, u16* __restrict__ Cp,
    int lda, int ldb, int ldc, int K,
    long sAb, long sAh, long sBb, long sBh, long sCb, long sCh, int numH) {
    __shared__ __align__(16) u16 As[TILE_M * LDSK];
    __shared__ __align__(16) u16 Bs[TILE_N * LDSK];
    int z = blockIdx.z;
    int bb = z / numH, hh = z % numH;
    const float* Af = Ap + (long)bb * sAb + (long)hh * sAh;
    const u16* Bb = Bp + (long)bb * sBb + (long)hh * sBh;
    long cOff = (long)bb * sCb + (long)hh * sCh;
    const int m0 = blockIdx.y * TILE_M, n0 = blockIdx.x * TILE_N;
    const int tid = threadIdx.x;
    const int lane = tid & 63, wave = tid >> 6;
    const int l15 = lane & 15, quad = lane >> 4;
    const int waveM = wave >> 1, waveN = wave & 1;
    f32x4 acc[4][4];
#pragma unroll
    for (int mt = 0; mt < 4; ++mt)
#pragma unroll
        for (int nt = 0; nt < 4; ++nt)
#pragma unroll
            for (int r = 0; r < 4; ++r) acc[mt][nt][r] = 0.f;
    for (int k0 = 0; k0 < K; k0 += TILE_K) {
#pragma unroll
        for (int i = 0; i < 2; ++i) {
            int c = tid + i * 256;
            int row = c >> 2, col = (c & 3) * 8;
            const float* src = Af + (size_t)(m0 + row) * lda + k0 + col;
            float4 f0 = *(const float4*)src;
            float4 f1 = *(const float4*)(src + 4);
            union { u16 u[8]; uint4 v; } pk;
            pk.u[0] = f2b(f0.x); pk.u[1] = f2b(f0.y); pk.u[2] = f2b(f0.z); pk.u[3] = f2b(f0.w);
            pk.u[4] = f2b(f1.x); pk.u[5] = f2b(f1.y); pk.u[6] = f2b(f1.z); pk.u[7] = f2b(f1.w);
            *(uint4*)&As[row * LDSK + col] = pk.v;
            *(uint4*)&Bs[row * LDSK + col] =
                *(const uint4*)(Bb + (size_t)(n0 + row) * ldb + k0 + col);
        }
        __syncthreads();
        bf16x8 av[4], bv[4];
#pragma unroll
        for (int t = 0; t < 4; ++t) {
            av[t] = *(bf16x8*)&As[(waveM * 64 + t * 16 + l15) * LDSK + quad * 8];
            bv[t] = *(bf16x8*)&Bs[(waveN * 64 + t * 16 + l15) * LDSK + quad * 8];
        }
#pragma unroll
        for (int mt = 0; mt < 4; ++mt)
#pragma unroll
            for (int nt = 0; nt < 4; ++nt)
                acc[mt][nt] = __builtin_amdgcn_mfma_f32_16x16x32_bf16(av[mt], bv[nt],
                                                                      acc[mt][nt], 0, 0, 0);
        __syncthreads();
    }
#pragma unroll
    for (int mt = 0; mt < 4; ++mt) {
        int row = m0 + waveM * 64 + mt * 16 + quad * 4;
#pragma unroll
        for (int nt = 0; nt < 4; ++nt) {
            int col = n0 + waveN * 64 + nt * 16 + l15;
#pragma unroll
            for (int r = 0; r < 4; ++r)
                Cp[cOff + (size_t)(row + r) * ldc + col] = f2b(acc[mt][nt][r]);
        }
    }
}

// ---------------- host launcher ----------------
extern "C" void kernel_launch(void* const* d_in, const int* in_sizes, int n_in,
                              void* d_out, int out_size, void* d_ws, size_t ws_size,
                              hipStream_t stream) {
    const float* hs   = (const float*)d_in[0];
    const float* mask = (const float*)d_in[1];
    const int*   pos  = (const int*)d_in[2];
    const float* Wq = (const float*)d_in[3];
    const float* bq = (const float*)d_in[4];
    const float* Wk = (const float*)d_in[5];
    const float* bk = (const float*)d_in[6];
    const float* Wv = (const float*)d_in[7];
    const float* bv = (const float*)d_in[8];
    const float* Wo = (const float*)d_in[9];
    const float* bo = (const float*)d_in[10];

    float* out  = (float*)d_out;                          // (B,S,HID)
    float* attn = (float*)d_out + (size_t)B_ * S_ * HID_; // (B,H,S,S)

    // workspace layout
    char* ws = (char*)d_ws;
    size_t need = 0;
    u16* hs_b    = (u16*)(ws);          need += (size_t)B_ * S_ * HID_ * 2;        // 16.8 MB (reused as ctx)
    u16* Wqkv_b  = (u16*)(ws + need);   need += (size_t)NQKV * HID_ * 2;           // 10.5 MB
    u16* Wo_b    = (u16*)(ws + need);   need += (size_t)HID_ * H_ * D_ * 2;        // 8.4 MB
    float* qkv_f = (float*)(ws + need); need += (size_t)B_ * S_ * NQKV * 4;        // 41.9 MB
    u16* q_b     = (u16*)(ws + need);   need += (size_t)B_ * S_ * H_ * D_ * 2;     // 16.8 MB
    u16* k_b     = (u16*)(ws + need);   need += (size_t)B_ * S_ * D_ * 2;          // 2.1 MB
    u16* vT_b    = (u16*)(ws + need);   need += (size_t)B_ * D_ * S_ * 2;          // 2.1 MB
    float* bqkv  = (float*)(ws + need); need += (size_t)NQKV * 4 + 4096;           // pad-align
    need &= ~(size_t)255;
    u16* attn_b  = (u16*)(ws + need);
    size_t need_big = need + (size_t)B_ * H_ * S_ * S_ * 2;                        // +134 MB
    bool big = ws_size >= need_big;
    u16* ctx_b = hs_b;                  // hs_b dead after QKV projection

    // 1) convert to bf16 (weights fused into one QKV buffer)
    cvt_bf16<<<dim3((B_ * S_ * HID_) / 1024), 256, 0, stream>>>(hs, hs_b, B_ * S_ * HID_);
    cvt_bf16<<<dim3((H_ * D_ * HID_) / 1024), 256, 0, stream>>>(Wq, Wqkv_b, H_ * D_ * HID_);
    cvt_bf16<<<dim3((D_ * HID_) / 1024), 256, 0, stream>>>(Wk, Wqkv_b + (size_t)H_ * D_ * HID_, D_ * HID_);
    cvt_bf16<<<dim3((D_ * HID_) / 1024), 256, 0, stream>>>(Wv, Wqkv_b + (size_t)(H_ * D_ + D_) * HID_, D_ * HID_);
    cvt_bf16<<<dim3((HID_ * H_ * D_) / 1024), 256, 0, stream>>>(Wo, Wo_b, HID_ * H_ * D_);
    concat_bias<<<dim3((NQKV + 255) / 256), 256, 0, stream>>>(bq, bk, bv, bqkv);

    // 2) fused QKV projection: (B*S, NQKV) = hs_b @ Wqkv^T + bqkv
    gemm_async<false><<<dim3(NQKV / TILE_N, (B_ * S_) / TILE_M, 1), 256, 0, stream>>>(
        hs_b, Wqkv_b, qkv_f, bqkv, HID_, HID_, NQKV, HID_,
        0, 0, 0, 0, 0, 0, 1);

    // 3) RoPE q,k ; transpose v
    rope_kernel<<<dim3((B_ * S_ * H_ * 128) / 256), 256, 0, stream>>>(
        qkv_f, NQKV, 0, pos, q_b, H_);
    rope_kernel<<<dim3((B_ * S_ * 1 * 128) / 256), 256, 0, stream>>>(
        qkv_f, NQKV, H_ * D_, pos, k_b, 1);
    transpose_v<<<dim3(S_ / 32, D_ / 32, B_), dim3(32, 8), 0, stream>>>(
        qkv_f, NQKV, H_ * D_ + D_, vT_b);

    // 4) scores = q @ k^T -> raw fp32 into attn region of d_out
    gemm_async<false><<<dim3(S_ / TILE_N, S_ / TILE_M, B_ * H_), 256, 0, stream>>>(
        q_b, k_b, attn, nullptr, H_ * D_, D_, S_, D_,
        (long)S_ * H_ * D_, D_,
        (long)S_ * D_, 0,
        (long)H_ * S_ * S_, (long)S_ * S_,
        H_);

    // 5) softmax in place (+ bf16 copy if ws allows)
    softmax_rows<<<dim3(B_ * H_ * S_), 256, 0, stream>>>(attn, mask, big ? attn_b : nullptr);

    // 6) ctx = attn @ V
    if (big) {
        gemm_async<true><<<dim3(D_ / TILE_N, S_ / TILE_M, B_ * H_), 256, 0, stream>>>(
            attn_b, vT_b, ctx_b, nullptr, S_, S_, H_ * D_, S_,
            (long)H_ * S_ * S_, (long)S_ * S_,
            (long)D_ * S_, 0,
            (long)S_ * H_ * D_, D_,
            H_);
    } else {
        gemm_slow_f32a<<<dim3(D_ / TILE_N, S_ / TILE_M, B_ * H_), 256, 0, stream>>>(
            attn, vT_b, ctx_b, S_, S_, H_ * D_, S_,
            (long)H_ * S_ * S_, (long)S_ * S_,
            (long)D_ * S_, 0,
            (long)S_ * H_ * D_, D_,
            H_);
    }

    // 7) out = ctx @ Wo^T + bo
    gemm_async<false><<<dim3(HID_ / TILE_N, (B_ * S_) / TILE_M, 1), 256, 0, stream>>>(
        ctx_b, Wo_b, out, bo, H_ * D_, H_ * D_, HID_, H_ * D_,
        0, 0, 0, 0, 0, 0, 1);
}